// Round 1
// baseline (303.840 us; speedup 1.0000x reference)
//
#include <hip/hip_runtime.h>

// TopKGate: x[T,2048] fp32, Wg[2048,64] fp32 -> gate_weights[T,64], top_idx[T,2] (as float), aux_loss
// T=16384, D=2048, E=64, K=2

constexpr int DD = 2048;
constexpr int EE = 64;
constexpr int TOK_PER_WAVE = 8;
constexpr int TPB_TOK = 32;      // tokens per block (4 waves)
constexpr int DCH = 64;          // d-chunk staged in LDS

__global__ __launch_bounds__(256) void gate_kernel(
    const float* __restrict__ x, const float* __restrict__ Wg,
    float* __restrict__ gate_out, float* __restrict__ idx_out,
    float* __restrict__ pSum, float* __restrict__ pCnt)
{
    __shared__ float xs[TPB_TOK][DCH];   // 8 KB
    const int tid  = threadIdx.x;
    const int wave = tid >> 6;
    const int lane = tid & 63;           // = expert id
    const int tok0 = blockIdx.x * TPB_TOK;

    float acc[TOK_PER_WAVE];
#pragma unroll
    for (int i = 0; i < TOK_PER_WAVE; ++i) acc[i] = 0.f;

    for (int dc = 0; dc < DD; dc += DCH) {
        __syncthreads();
        // stage 32 tokens x 64 d's: 512 float4's, 256 threads -> 2 each, coalesced
#pragma unroll
        for (int r = 0; r < 2; ++r) {
            int fidx = tid + r * 256;          // float4 index
            int t    = fidx >> 4;              // 16 float4 per token row
            int dd   = (fidx & 15) << 2;
            *(float4*)&xs[t][dd] =
                *(const float4*)&x[(size_t)(tok0 + t) * DD + dc + dd];
        }
        __syncthreads();

#pragma unroll
        for (int dd = 0; dd < DCH; dd += 4) {
            float w0 = Wg[(size_t)(dc + dd + 0) * EE + lane];
            float w1 = Wg[(size_t)(dc + dd + 1) * EE + lane];
            float w2 = Wg[(size_t)(dc + dd + 2) * EE + lane];
            float w3 = Wg[(size_t)(dc + dd + 3) * EE + lane];
#pragma unroll
            for (int tt = 0; tt < TOK_PER_WAVE; ++tt) {
                float4 xv = *(float4*)&xs[wave * TOK_PER_WAVE + tt][dd];
                acc[tt] = fmaf(xv.x, w0, acc[tt]);
                acc[tt] = fmaf(xv.y, w1, acc[tt]);
                acc[tt] = fmaf(xv.z, w2, acc[tt]);
                acc[tt] = fmaf(xv.w, w3, acc[tt]);
            }
        }
    }

    // ---- per-token softmax + top-2 (lane = expert) ----
    float sumP_acc = 0.f;
    float cnt_acc  = 0.f;
#pragma unroll 1
    for (int tt = 0; tt < TOK_PER_WAVE; ++tt) {
        const int t = tok0 + wave * TOK_PER_WAVE + tt;
        float v = acc[tt];

        float m = v;
#pragma unroll
        for (int off = 32; off; off >>= 1) m = fmaxf(m, __shfl_xor(m, off, 64));
        float p = expf(v - m);
        float s = p;
#pragma unroll
        for (int off = 32; off; off >>= 1) s += __shfl_xor(s, off, 64);
        float prob = p / s;
        sumP_acc += prob;

        // top-1 (ties -> lowest index, matches lax.top_k)
        float bv = prob; int bi = lane;
#pragma unroll
        for (int off = 32; off; off >>= 1) {
            float ov = __shfl_xor(bv, off, 64);
            int   oi = __shfl_xor(bi, off, 64);
            if (ov > bv || (ov == bv && oi < bi)) { bv = ov; bi = oi; }
        }
        // top-2
        float v2 = (lane == bi) ? -1.f : prob;   // probs >= 0
        float bv2 = v2; int bi2 = lane;
#pragma unroll
        for (int off = 32; off; off >>= 1) {
            float ov = __shfl_xor(bv2, off, 64);
            int   oi = __shfl_xor(bi2, off, 64);
            if (ov > bv2 || (ov == bv2 && oi < bi2)) { bv2 = ov; bi2 = oi; }
        }

        float denom = bv + bv2;
        float g1 = bv / denom, g2 = bv2 / denom;
        float g = (lane == bi) ? g1 : ((lane == bi2) ? g2 : 0.f);
        gate_out[(size_t)t * EE + lane] = g;
        if (lane == 0) {
            idx_out[2 * t]     = (float)bi;
            idx_out[2 * t + 1] = (float)bi2;
        }
        cnt_acc += (lane == bi)  ? 1.f : 0.f;
        cnt_acc += (lane == bi2) ? 1.f : 0.f;
    }

    // ---- per-block partials for aux loss (deterministic, no atomics) ----
    __syncthreads();
    float* sm = (float*)xs;
    sm[wave * 64 + lane]       = sumP_acc;
    sm[(4 + wave) * 64 + lane] = cnt_acc;
    __syncthreads();
    if (wave == 0) {
        float sp = 0.f, c = 0.f;
#pragma unroll
        for (int w = 0; w < 4; ++w) {
            sp += sm[w * 64 + lane];
            c  += sm[(4 + w) * 64 + lane];
        }
        pSum[(size_t)blockIdx.x * 64 + lane] = sp;
        pCnt[(size_t)blockIdx.x * 64 + lane] = c;
    }
}

__global__ __launch_bounds__(64) void aux_kernel(
    const float* __restrict__ pSum, const float* __restrict__ pCnt,
    float* __restrict__ aux_out, int nblocks, float scale)
{
    const int lane = threadIdx.x;
    float sp = 0.f, c = 0.f;
    for (int b = 0; b < nblocks; ++b) {
        sp += pSum[(size_t)b * 64 + lane];
        c  += pCnt[(size_t)b * 64 + lane];
    }
    float prod = sp * c;
#pragma unroll
    for (int off = 32; off; off >>= 1) prod += __shfl_xor(prod, off, 64);
    if (lane == 0) aux_out[0] = prod * scale;
}

extern "C" void kernel_launch(void* const* d_in, const int* in_sizes, int n_in,
                              void* d_out, int out_size, void* d_ws, size_t ws_size,
                              hipStream_t stream) {
    const float* x  = (const float*)d_in[0];
    const float* Wg = (const float*)d_in[1];
    const int T = in_sizes[0] / DD;          // 16384

    float* out      = (float*)d_out;
    float* gate_out = out;                                // T*64
    float* idx_out  = out + (size_t)T * EE;               // T*2 (as float)
    float* aux_out  = idx_out + (size_t)T * 2;            // 1

    const int nblocks = T / TPB_TOK;                      // 512
    float* pSum = (float*)d_ws;                           // nblocks*64
    float* pCnt = pSum + (size_t)nblocks * 64;            // nblocks*64

    gate_kernel<<<nblocks, 256, 0, stream>>>(x, Wg, gate_out, idx_out, pSum, pCnt);

    const float scale = (float)EE / ((float)T * (float)T);
    aux_kernel<<<1, 64, 0, stream>>>(pSum, pCnt, aux_out, nblocks, scale);
}

// Round 2
// 180.887 us; speedup vs baseline: 1.6797x; 1.6797x over previous
//
#include <hip/hip_runtime.h>

// TopKGate: x[16384,2048] fp32, Wg[2048,64] fp32 ->
//   gate_weights[T,64], top_idx[T,2] (as float), aux_loss (1 float)

constexpr int DD = 2048;
constexpr int EE = 64;
constexpr int DCH = 64;          // d-chunk
constexpr int TPB_TOK = 32;      // tokens per block (4 waves x 8 tokens)

__global__ __launch_bounds__(256, 2) void gate_kernel(
    const float* __restrict__ x, const float* __restrict__ Wg,
    float* __restrict__ gate_out, float* __restrict__ idx_out,
    float* __restrict__ pSum, float* __restrict__ pCnt)
{
    // LDS: Wg dbuf 2x16KB + x dbuf 2x8KB = 48 KB
    __shared__ __align__(16) float lds[2 * DCH * EE + 2 * TPB_TOK * DCH];
    float* wgL = lds;                  // [2][DCH*EE]   layout [dd][e]
    float* xsL = lds + 2 * DCH * EE;   // [2][TPB_TOK*DCH] layout [t][dd]

    const int tid  = threadIdx.x;
    const int wave = tid >> 6;
    const int lane = tid & 63;          // = expert id
    const size_t tok0 = (size_t)blockIdx.x * TPB_TOK;

    float acc[8];
#pragma unroll
    for (int i = 0; i < 8; ++i) acc[i] = 0.f;

    // ---- async stage of one chunk (6 x global_load_lds dwordx4 per thread) ----
    auto stage = [&](int buf, int dc) {
        const float* wsrc = Wg + (size_t)dc * EE;
        float* wdst = wgL + buf * (DCH * EE);
#pragma unroll
        for (int r = 0; r < 4; ++r) {
            int j = tid + r * 256;                       // float4 slot, linear in tid
            __builtin_amdgcn_global_load_lds(wsrc + (size_t)j * 4, wdst + j * 4, 16, 0, 0);
        }
        const float* xbase = x + tok0 * DD + dc;
        float* xdst = xsL + buf * (TPB_TOK * DCH);
#pragma unroll
        for (int r = 0; r < 2; ++r) {
            int i = tid + r * 256;                       // float4 slot, linear in tid
            int t = i >> 4, dq = (i & 15) << 2;
            __builtin_amdgcn_global_load_lds(xbase + (size_t)t * DD + dq, xdst + i * 4, 16, 0, 0);
        }
    };

    stage(0, 0);
    __syncthreads();                                     // drains vmcnt incl. our loads

    int buf = 0;
    for (int dc = 0; dc < DD; dc += DCH) {
        if (dc + DCH < DD) stage(buf ^ 1, dc + DCH);     // prefetch next chunk

        // Wg chunk -> 64 VGPRs: conflict-free ds_read_b32, offsets fold (dd*256B)
        float w[DCH];
        const float* wp = wgL + buf * (DCH * EE) + lane;
#pragma unroll
        for (int dd = 0; dd < DCH; ++dd) w[dd] = wp[(size_t)dd * EE];

        // x: uniform-address ds_read_b128 broadcasts, offsets fold
        const float* xp = xsL + buf * (TPB_TOK * DCH) + (wave * 8) * DCH;
#pragma unroll
        for (int tt = 0; tt < 8; ++tt) {
#pragma unroll
            for (int g = 0; g < 16; ++g) {
                float4 xv = *(const float4*)(xp + tt * DCH + g * 4);
                acc[tt] = fmaf(xv.x, w[4 * g + 0], acc[tt]);
                acc[tt] = fmaf(xv.y, w[4 * g + 1], acc[tt]);
                acc[tt] = fmaf(xv.z, w[4 * g + 2], acc[tt]);
                acc[tt] = fmaf(xv.w, w[4 * g + 3], acc[tt]);
            }
        }
        __syncthreads();       // waits vmcnt(0): next chunk landed; buf safe to overwrite
        buf ^= 1;
    }

    // ---- per-token softmax + top-2 (lane = expert) ----
    float sumP_acc = 0.f;
    float cnt_acc  = 0.f;
#pragma unroll 1
    for (int tt = 0; tt < 8; ++tt) {
        const size_t t = tok0 + wave * 8 + tt;
        float v = acc[tt];

        float m = v;
#pragma unroll
        for (int off = 32; off; off >>= 1) m = fmaxf(m, __shfl_xor(m, off, 64));
        float p = expf(v - m);
        float s = p;
#pragma unroll
        for (int off = 32; off; off >>= 1) s += __shfl_xor(s, off, 64);
        float prob = p / s;
        sumP_acc += prob;

        // top-1 (ties -> lowest index, matches lax.top_k)
        float bv = prob; int bi = lane;
#pragma unroll
        for (int off = 32; off; off >>= 1) {
            float ov = __shfl_xor(bv, off, 64);
            int   oi = __shfl_xor(bi, off, 64);
            if (ov > bv || (ov == bv && oi < bi)) { bv = ov; bi = oi; }
        }
        // top-2
        float v2 = (lane == bi) ? -1.f : prob;
        float bv2 = v2; int bi2 = lane;
#pragma unroll
        for (int off = 32; off; off >>= 1) {
            float ov = __shfl_xor(bv2, off, 64);
            int   oi = __shfl_xor(bi2, off, 64);
            if (ov > bv2 || (ov == bv2 && oi < bi2)) { bv2 = ov; bi2 = oi; }
        }

        float denom = bv + bv2;
        float g1 = bv / denom, g2 = bv2 / denom;
        float g = (lane == bi) ? g1 : ((lane == bi2) ? g2 : 0.f);
        gate_out[t * EE + lane] = g;
        if (lane == 0) {
            idx_out[2 * t]     = (float)bi;
            idx_out[2 * t + 1] = (float)bi2;
        }
        cnt_acc += (lane == bi)  ? 1.f : 0.f;
        cnt_acc += (lane == bi2) ? 1.f : 0.f;
    }

    // ---- per-block partials for aux loss (deterministic, no atomics) ----
    __syncthreads();
    float* sm = lds;
    sm[wave * 64 + lane]       = sumP_acc;
    sm[(4 + wave) * 64 + lane] = cnt_acc;
    __syncthreads();
    if (wave == 0) {
        float sp = 0.f, c = 0.f;
#pragma unroll
        for (int w = 0; w < 4; ++w) {
            sp += sm[w * 64 + lane];
            c  += sm[(4 + w) * 64 + lane];
        }
        pSum[(size_t)blockIdx.x * 64 + lane] = sp;
        pCnt[(size_t)blockIdx.x * 64 + lane] = c;
    }
}

// parallel aux reduction: 1024 threads (16 waves), strided partial loop + LDS reduce
__global__ __launch_bounds__(1024) void aux_kernel(
    const float* __restrict__ pSum, const float* __restrict__ pCnt,
    float* __restrict__ aux_out, int nblocks, float scale)
{
    const int tid  = threadIdx.x;
    const int wv   = tid >> 6;       // 0..15
    const int lane = tid & 63;       // = expert id
    __shared__ float sm[2][16][64];

    float sp = 0.f, c = 0.f;
    for (int b = wv; b < nblocks; b += 16) {
        sp += pSum[(size_t)b * 64 + lane];
        c  += pCnt[(size_t)b * 64 + lane];
    }
    sm[0][wv][lane] = sp;
    sm[1][wv][lane] = c;
    __syncthreads();
    if (wv == 0) {
        float SP = 0.f, C = 0.f;
#pragma unroll
        for (int w = 0; w < 16; ++w) {
            SP += sm[0][w][lane];
            C  += sm[1][w][lane];
        }
        float prod = SP * C;
#pragma unroll
        for (int off = 32; off; off >>= 1) prod += __shfl_xor(prod, off, 64);
        if (lane == 0) aux_out[0] = prod * scale;
    }
}

extern "C" void kernel_launch(void* const* d_in, const int* in_sizes, int n_in,
                              void* d_out, int out_size, void* d_ws, size_t ws_size,
                              hipStream_t stream) {
    const float* x  = (const float*)d_in[0];
    const float* Wg = (const float*)d_in[1];
    const int T = in_sizes[0] / DD;          // 16384

    float* out      = (float*)d_out;
    float* gate_out = out;                                // T*64
    float* idx_out  = out + (size_t)T * EE;               // T*2 (as float)
    float* aux_out  = idx_out + (size_t)T * 2;            // 1

    const int nblocks = T / TPB_TOK;                      // 512
    float* pSum = (float*)d_ws;                           // nblocks*64
    float* pCnt = pSum + (size_t)nblocks * 64;            // nblocks*64

    gate_kernel<<<nblocks, 256, 0, stream>>>(x, Wg, gate_out, idx_out, pSum, pCnt);

    const float scale = (float)EE / ((float)T * (float)T);
    aux_kernel<<<1, 1024, 0, stream>>>(pSum, pCnt, aux_out, nblocks, scale);
}

// Round 3
// 180.555 us; speedup vs baseline: 1.6828x; 1.0018x over previous
//
#include <hip/hip_runtime.h>

// TopKGate: x[16384,2048] fp32, Wg[2048,64] fp32 ->
//   gate_weights[T,64], top_idx[T,2] (as float), aux_loss (1 float)

constexpr int DD = 2048;
constexpr int EE = 64;
constexpr int DCH = 64;          // d-chunk
constexpr int TPB_TOK = 16;      // tokens per block (2 waves x 8 tokens)
constexpr int NCH = DD / DCH;    // 32 chunks

// counted-vmcnt barrier: leave next chunk's loads in flight (T4)
#define WAIT_VM_BARRIER(N) asm volatile("s_waitcnt vmcnt(" #N ")\n\ts_barrier" ::: "memory")
#define LGKM_BARRIER()     asm volatile("s_waitcnt lgkmcnt(0)\n\ts_barrier" ::: "memory")

__global__ __launch_bounds__(128, 2) void gate_kernel(
    const float* __restrict__ x, const float* __restrict__ Wg,
    float* __restrict__ gate_out, float* __restrict__ idx_out,
    float* __restrict__ pSum, float* __restrict__ pCnt)
{
    // 40 KB total -> 4 blocks/CU
    __shared__ __align__(16) float wgL[2][DCH * EE];       // 2 x 16 KB, layout [dd][e]
    __shared__ __align__(16) float xsL[2][TPB_TOK * DCH];  // 2 x 4 KB,  layout [t][dd]

    const int tid  = threadIdx.x;
    const int wave = tid >> 6;          // 0..1
    const int lane = tid & 63;          // = expert id
    const size_t tok0 = (size_t)blockIdx.x * TPB_TOK;

    // stage one chunk: 8x Wg + 2x x global_load_lds dwordx4 per thread (10 loads)
    auto stage = [&](int b, int dc) {
        const float* wsrc = Wg + (size_t)dc * EE;
        float* wdst = &wgL[b][0];
#pragma unroll
        for (int r = 0; r < 8; ++r) {
            int j = tid + r * 128;                       // float4 slot, linear in tid
            __builtin_amdgcn_global_load_lds(wsrc + (size_t)j * 4, wdst + j * 4, 16, 0, 0);
        }
        const float* xbase = x + tok0 * DD + dc;
        float* xdst = &xsL[b][0];
#pragma unroll
        for (int r = 0; r < 2; ++r) {
            int j = tid + r * 128;                       // float4 slot, linear in tid
            int t = j >> 4, dq = (j & 15) << 2;
            __builtin_amdgcn_global_load_lds(xbase + (size_t)t * DD + dq, xdst + j * 4, 16, 0, 0);
        }
    };

    float acc[8];
#pragma unroll
    for (int i = 0; i < 8; ++i) acc[i] = 0.f;

    stage(0, 0);
    int buf = 0;
#pragma unroll 1
    for (int ci = 0; ci < NCH; ++ci) {
        if (ci + 1 < NCH) {
            stage(buf ^ 1, (ci + 1) * DCH);   // 10 more loads in flight
            WAIT_VM_BARRIER(10);              // chunk ci landed; ci+1 still flying
        } else {
            WAIT_VM_BARRIER(0);
        }

        // dd-outer: only 4 w values live; acc[8] accumulates; x broadcast reads
        const float*  wp = &wgL[buf][0] + lane;
        const float4* xq = (const float4*)&xsL[buf][(wave * 8) * DCH];
#pragma unroll
        for (int g = 0; g < 16; ++g) {
            const float w0 = wp[(4 * g + 0) * EE];
            const float w1 = wp[(4 * g + 1) * EE];
            const float w2 = wp[(4 * g + 2) * EE];
            const float w3 = wp[(4 * g + 3) * EE];
#pragma unroll
            for (int tt = 0; tt < 8; ++tt) {
                float4 xv = xq[tt * 16 + g];
                acc[tt] = fmaf(xv.x, w0, acc[tt]);
                acc[tt] = fmaf(xv.y, w1, acc[tt]);
                acc[tt] = fmaf(xv.z, w2, acc[tt]);
                acc[tt] = fmaf(xv.w, w3, acc[tt]);
            }
        }
        LGKM_BARRIER();                       // all waves done reading buf
        buf ^= 1;
    }

    // ---- per-token softmax + top-2 (lane = expert) ----
    float sumP_acc = 0.f;
    float cnt_acc  = 0.f;
#pragma unroll 1
    for (int tt = 0; tt < 8; ++tt) {
        const size_t t = tok0 + wave * 8 + tt;
        float v = acc[tt];

        float m = v;
#pragma unroll
        for (int off = 32; off; off >>= 1) m = fmaxf(m, __shfl_xor(m, off, 64));
        float p = expf(v - m);
        float s = p;
#pragma unroll
        for (int off = 32; off; off >>= 1) s += __shfl_xor(s, off, 64);
        float prob = p / s;
        sumP_acc += prob;

        // top-1 (ties -> lowest index, matches lax.top_k)
        float bv = prob; int bi = lane;
#pragma unroll
        for (int off = 32; off; off >>= 1) {
            float ov = __shfl_xor(bv, off, 64);
            int   oi = __shfl_xor(bi, off, 64);
            if (ov > bv || (ov == bv && oi < bi)) { bv = ov; bi = oi; }
        }
        // top-2
        float v2 = (lane == bi) ? -1.f : prob;
        float bv2 = v2; int bi2 = lane;
#pragma unroll
        for (int off = 32; off; off >>= 1) {
            float ov = __shfl_xor(bv2, off, 64);
            int   oi = __shfl_xor(bi2, off, 64);
            if (ov > bv2 || (ov == bv2 && oi < bi2)) { bv2 = ov; bi2 = oi; }
        }

        float denom = bv + bv2;
        float g1 = bv / denom, g2 = bv2 / denom;
        float g = (lane == bi) ? g1 : ((lane == bi2) ? g2 : 0.f);
        gate_out[t * EE + lane] = g;
        if (lane == 0) {
            idx_out[2 * t]     = (float)bi;
            idx_out[2 * t + 1] = (float)bi2;
        }
        cnt_acc += (lane == bi)  ? 1.f : 0.f;
        cnt_acc += (lane == bi2) ? 1.f : 0.f;
    }

    // ---- per-block partials for aux loss (deterministic, no atomics) ----
    float* sm = &wgL[0][0];                  // reuse LDS
    __syncthreads();
    sm[wave * 64 + lane]       = sumP_acc;
    sm[(2 + wave) * 64 + lane] = cnt_acc;
    __syncthreads();
    if (wave == 0) {
        float sp = sm[0 * 64 + lane] + sm[1 * 64 + lane];
        float c  = sm[2 * 64 + lane] + sm[3 * 64 + lane];
        pSum[(size_t)blockIdx.x * 64 + lane] = sp;
        pCnt[(size_t)blockIdx.x * 64 + lane] = c;
    }
}

// parallel aux reduction: 1024 threads (16 waves), 4-deep ILP partial loop + LDS reduce
__global__ __launch_bounds__(1024) void aux_kernel(
    const float* __restrict__ pSum, const float* __restrict__ pCnt,
    float* __restrict__ aux_out, int nblocks, float scale)
{
    const int tid  = threadIdx.x;
    const int wv   = tid >> 6;       // 0..15
    const int lane = tid & 63;       // = expert id
    __shared__ float smem[2][16][64];

    float sp[4] = {0.f, 0.f, 0.f, 0.f};
    float cc[4] = {0.f, 0.f, 0.f, 0.f};
    for (int b = wv * 4; b < nblocks; b += 64) {
#pragma unroll
        for (int u = 0; u < 4; ++u) {
            sp[u] += pSum[(size_t)(b + u) * 64 + lane];
            cc[u] += pCnt[(size_t)(b + u) * 64 + lane];
        }
    }
    smem[0][wv][lane] = (sp[0] + sp[1]) + (sp[2] + sp[3]);
    smem[1][wv][lane] = (cc[0] + cc[1]) + (cc[2] + cc[3]);
    __syncthreads();
    if (wv == 0) {
        float SP = 0.f, C = 0.f;
#pragma unroll
        for (int w = 0; w < 16; ++w) {
            SP += smem[0][w][lane];
            C  += smem[1][w][lane];
        }
        float prod = SP * C;
#pragma unroll
        for (int off = 32; off; off >>= 1) prod += __shfl_xor(prod, off, 64);
        if (lane == 0) aux_out[0] = prod * scale;
    }
}

extern "C" void kernel_launch(void* const* d_in, const int* in_sizes, int n_in,
                              void* d_out, int out_size, void* d_ws, size_t ws_size,
                              hipStream_t stream) {
    const float* x  = (const float*)d_in[0];
    const float* Wg = (const float*)d_in[1];
    const int T = in_sizes[0] / DD;          // 16384

    float* out      = (float*)d_out;
    float* gate_out = out;                                // T*64
    float* idx_out  = out + (size_t)T * EE;               // T*2 (as float)
    float* aux_out  = idx_out + (size_t)T * 2;            // 1

    const int nblocks = T / TPB_TOK;                      // 1024
    float* pSum = (float*)d_ws;                           // nblocks*64
    float* pCnt = pSum + (size_t)nblocks * 64;            // nblocks*64

    gate_kernel<<<nblocks, 128, 0, stream>>>(x, Wg, gate_out, idx_out, pSum, pCnt);

    const float scale = (float)EE / ((float)T * (float)T);
    aux_kernel<<<1, 1024, 0, stream>>>(pSum, pCnt, aux_out, nblocks, scale);
}